// Round 11
// baseline (133.777 us; speedup 1.0000x reference)
//
#include <hip/hip_runtime.h>

constexpr int B = 64;
constexpr int N = 8192;
constexpr int D = 256;
constexpr int K = 128;
constexpr int CHUNKS = 32;                 // chunks per batch
constexpr int RPC = N / CHUNKS;            // 256 rows per chunk (per block)
constexpr int NCAND = CHUNKS * K;          // 4096 candidates per batch
constexpr int TILE = 64;                   // rows per LDS tile (4 tiles/block)
constexpr int REPS = 4;                    // DIAGNOSTIC (round-7 technique):
                                           // x4 idempotent re-run of stage-1
                                           // body. Per-rep time vs L3-hit rate
                                           // decides latency- vs BW-bound.

typedef unsigned long long ull;

__device__ __forceinline__ int bitrev6(int l) {
    return ((l & 1) << 5) | ((l & 2) << 3) | ((l & 4) << 1)
         | ((l & 8) >> 1) | ((l & 16) >> 3) | ((l & 32) >> 5);
}

// --- Stage 1: norm + local top-K (round-8 body, x REPS diagnostic) ----------
// Keys bit-identical to all passing rounds (bitrev column placement +
// balanced-tree fold == rounds-1-4 butterfly bitwise).
__global__ __launch_bounds__(256) void norm_select_kernel(const float* __restrict__ x,
                                                          ull* __restrict__ cand) {
    __shared__ float part[TILE][65];              // 16.6 KiB, stride-65 pad
    __shared__ ull skeys[RPC];                    // 2 KiB
    const int bid   = blockIdx.x;
    const int batch = bid >> 5;                   // / CHUNKS
    const int chunk = bid & (CHUNKS - 1);
    const int tid   = threadIdx.x;
    const int w     = tid >> 6;
    const int lane  = tid & 63;
    const int brl   = bitrev6(lane);
    const size_t rowbase = (size_t)batch * N + (size_t)chunk * RPC;

    #pragma unroll 1
    for (int rep = 0; rep < REPS; ++rep) {
        for (int tile = 0; tile < 4; ++tile) {
            const int r0 = w * 16;                // wave's first row in tile
            const float* wbase = x + (rowbase + (size_t)(tile * TILE + r0)) * D;
            #pragma unroll
            for (int it0 = 0; it0 < 16; it0 += 4) {
                float4 v[4];
                #pragma unroll
                for (int u = 0; u < 4; ++u)
                    v[u] = reinterpret_cast<const float4*>(wbase + (size_t)(it0 + u) * D)[lane];
                #pragma unroll
                for (int u = 0; u < 4; ++u)
                    part[r0 + it0 + u][brl] = v[u].x * v[u].x + v[u].y * v[u].y
                                            + v[u].z * v[u].z + v[u].w * v[u].w;
            }
            __syncthreads();

            // Phase 2: thread t (<64) folds row t's 64 partials, balanced tree.
            if (tid < TILE) {
                float q[8];
                float g[8];
                #pragma unroll
                for (int grp = 0; grp < 8; ++grp) {
                    #pragma unroll
                    for (int j = 0; j < 8; ++j) q[j] = part[tid][grp * 8 + j];
                    g[grp] = ((q[0] + q[1]) + (q[2] + q[3]))
                           + ((q[4] + q[5]) + (q[6] + q[7]));
                }
                const float s = ((g[0] + g[1]) + (g[2] + g[3]))
                              + ((g[4] + g[5]) + (g[6] + g[7]));
                const int grow = chunk * RPC + tile * TILE + tid;   // row in batch
                skeys[tile * TILE + tid] = ((ull)__float_as_uint(s) << 32)
                                         | (unsigned int)(N - 1 - grow);
            }
            __syncthreads();                      // part[] reused next tile
        }

        // All-pairs rank among 256 distinct keys; top 128 self-place by rank.
        const ull mine = skeys[tid];
        int rank = 0;
        for (int j = 0; j < RPC; ++j)
            rank += (skeys[j] > mine) ? 1 : 0;
        if (rank < K)
            cand[(size_t)bid * K + rank] = mine;  // same value every rep
        __syncthreads();                          // skeys stable across reps
    }
}

// --- Stage 2: exact top-K select over 4096 candidates (indices only) --------
// (BYTE-IDENTICAL to rounds 9-10.)
__global__ __launch_bounds__(1024) void topk_select_kernel(const ull* __restrict__ cand_in,
                                                           int* __restrict__ idx_out) {
    __shared__ ull keys[NCAND];                   // 32 KiB
    __shared__ unsigned int hist[256];
    __shared__ unsigned int seg[32];
    __shared__ ull s_prefix;
    __shared__ unsigned int s_krem;
    __shared__ int s_done;
    __shared__ unsigned int s_cnt;
    __shared__ ull sel[K];

    const int b    = blockIdx.x;
    const int tid  = threadIdx.x;
    const int lane = tid & 63;

    for (int i = tid; i < NCAND; i += 1024)
        keys[i] = cand_in[(size_t)b * NCAND + i];
    if (tid == 0) { s_prefix = 0ull; s_krem = K; s_done = 0; s_cnt = 0u; }
    __syncthreads();

    for (int p = 7; p >= 0; --p) {
        if (s_done) break;                         // uniform, barrier-separated
        const int shift = p * 8;
        const ull          prefix = s_prefix;
        const unsigned int krem   = s_krem;
        if (tid < 256) hist[tid] = 0u;
        __syncthreads();

        if (p == 7) {
            for (int i = tid; i < NCAND; i += 1024) {
                const unsigned int d = (unsigned int)(keys[i] >> 56);
                ull rem = __ballot(true);
                while (rem) {
                    const int leader = __ffsll(rem) - 1;
                    const unsigned int dl = __shfl(d, leader, 64);
                    const ull grp = __ballot(d == dl);
                    if (lane == leader) atomicAdd(&hist[dl], (unsigned int)__popcll(grp));
                    rem &= ~grp;
                }
            }
        } else {
            for (int i = tid; i < NCAND; i += 1024) {
                const ull key = keys[i];
                if ((key >> (shift + 8)) == (prefix >> (shift + 8)))
                    atomicAdd(&hist[(unsigned int)(key >> shift) & 255u], 1u);
            }
        }
        __syncthreads();

        if (tid < 32) {                            // segment sums of 8 bins
            unsigned int s = 0;
            #pragma unroll
            for (int d2 = 0; d2 < 8; ++d2) s += hist[tid * 8 + d2];
            seg[tid] = s;
        }
        __syncthreads();

        if (tid < 256) {
            unsigned int cnt_gt = 0;
            const int hiSeg = (tid >> 3) + 1;
            for (int s2 = hiSeg; s2 < 32; ++s2) cnt_gt += seg[s2];
            for (int d2 = tid + 1; d2 < hiSeg * 8; ++d2) cnt_gt += hist[d2];
            const unsigned int h = hist[tid];
            if (cnt_gt < krem && krem <= cnt_gt + h) {   // unique winner
                s_prefix = prefix | ((ull)tid << shift);
                s_krem   = krem - cnt_gt;
                if (h == krem - cnt_gt) s_done = 1;
            }
        }
        __syncthreads();
    }

    const ull T = s_prefix;
    for (int i = tid; i < NCAND; i += 1024) {
        const ull key = keys[i];
        if (key >= T) {
            const unsigned int pos = atomicAdd(&s_cnt, 1u);
            sel[pos] = key;
        }
    }
    __syncthreads();

    if (tid < K) {
        const ull key = sel[tid];
        int rank = 0;
        for (int j = 0; j < K; ++j) rank += (sel[j] > key) ? 1 : 0;
        idx_out[b * K + rank] = N - 1 - (int)(key & 0xFFFFFFFFu);
    }
}

// --- Stage 3: full-grid gather (BYTE-IDENTICAL to rounds 9-10) --------------
__global__ __launch_bounds__(256) void gather_kernel(const float* __restrict__ x,
                                                     const int* __restrict__ idx,
                                                     float* __restrict__ out) {
    const int row  = blockIdx.x * 4 + (threadIdx.x >> 6);    // 0 .. B*K-1
    const int lane = threadIdx.x & 63;
    const int b    = row >> 7;                                // / K
    const int src  = idx[row];
    const float4 v = reinterpret_cast<const float4*>(x + ((size_t)b * N + src) * D)[lane];
    reinterpret_cast<float4*>(out + (size_t)row * D)[lane] = v;
}

extern "C" void kernel_launch(void* const* d_in, const int* in_sizes, int n_in,
                              void* d_out, int out_size, void* d_ws, size_t ws_size,
                              hipStream_t stream) {
    const float* x = (const float*)d_in[0];
    float* out = (float*)d_out;
    ull* cand = (ull*)d_ws;                        // B*NCAND u64 = 2 MiB
    int* idx  = (int*)(cand + (size_t)B * NCAND);  // B*K int = 32 KiB

    norm_select_kernel<<<B * CHUNKS, 256, 0, stream>>>(x, cand);
    topk_select_kernel<<<B, 1024, 0, stream>>>(cand, idx);
    gather_kernel<<<B * K / 4, 256, 0, stream>>>(x, idx, out);
}

// Round 13
// 104.956 us; speedup vs baseline: 1.2746x; 1.2746x over previous
//
#include <hip/hip_runtime.h>

constexpr int B = 64;
constexpr int N = 8192;
constexpr int D = 256;
constexpr int K = 128;
constexpr int CHUNKS = 32;                 // chunks per batch
constexpr int RPC = N / CHUNKS;            // 256 rows per chunk (per block)
constexpr int NCAND = CHUNKS * K;          // 4096 candidates per batch
constexpr int TILE = 64;                   // rows per LDS tile (4 tiles/block)

typedef unsigned long long ull;
typedef float f4 __attribute__((ext_vector_type(4)));   // true vector type:
                                                        // accepted by
                                                        // __builtin_nontemporal_*

__device__ __forceinline__ int bitrev6(int l) {
    return ((l & 1) << 5) | ((l & 2) << 3) | ((l & 4) << 1)
         | ((l & 8) >> 1) | ((l & 16) >> 3) | ((l & 32) >> 5);
}

// --- Stage 1: norm + local top-K (round-8/10 body + NT loads) ---------------
// x is streamed exactly once; nontemporal loads set the nt cache bit so the
// 512 MB stream doesn't allocate/evict through L2/L3 (zero reuse value).
// Round-11 REPS diagnostic: non-load work is only ~6us; loads ~96us at
// ~5.6 TB/s -- all remaining cost is the read stream itself.
// BIT-EXACTNESS: lane partial x*x+y*y+z*z+w*w written at column bitrev6(lane);
// balanced-tree fold == rounds-1-4 butterfly bitwise. NT changes caching only,
// not values -> keys bit-identical, selection provably unchanged.
__global__ __launch_bounds__(256) void norm_select_kernel(const float* __restrict__ x,
                                                          ull* __restrict__ cand) {
    __shared__ float part[TILE][65];              // 16.6 KiB, stride-65 pad
    __shared__ ull skeys[RPC];                    // 2 KiB
    const int bid   = blockIdx.x;
    const int batch = bid >> 5;                   // / CHUNKS
    const int chunk = bid & (CHUNKS - 1);
    const int tid   = threadIdx.x;
    const int w     = tid >> 6;
    const int lane  = tid & 63;
    const int brl   = bitrev6(lane);
    const size_t rowbase = (size_t)batch * N + (size_t)chunk * RPC;

    for (int tile = 0; tile < 4; ++tile) {
        // Wave w streams its 16 rows of this tile: load->VALU->ds_write only.
        const int r0 = w * 16;                    // wave's first row in tile
        const float* wbase = x + (rowbase + (size_t)(tile * TILE + r0)) * D;
        #pragma unroll
        for (int it0 = 0; it0 < 16; it0 += 4) {
            f4 v[4];
            #pragma unroll
            for (int u = 0; u < 4; ++u)
                v[u] = __builtin_nontemporal_load(
                           reinterpret_cast<const f4*>(wbase + (size_t)(it0 + u) * D) + lane);
            #pragma unroll
            for (int u = 0; u < 4; ++u)
                part[r0 + it0 + u][brl] = v[u].x * v[u].x + v[u].y * v[u].y
                                        + v[u].z * v[u].z + v[u].w * v[u].w;
        }
        __syncthreads();

        // Phase 2: thread t (<64) folds row t's 64 partials as the standard
        // balanced tree (== butterfly bits). Reads stride-65: conflict-free.
        if (tid < TILE) {
            float q[8];
            float g[8];
            #pragma unroll
            for (int grp = 0; grp < 8; ++grp) {
                #pragma unroll
                for (int j = 0; j < 8; ++j) q[j] = part[tid][grp * 8 + j];
                g[grp] = ((q[0] + q[1]) + (q[2] + q[3]))
                       + ((q[4] + q[5]) + (q[6] + q[7]));
            }
            const float s = ((g[0] + g[1]) + (g[2] + g[3]))
                          + ((g[4] + g[5]) + (g[6] + g[7]));
            const int grow = chunk * RPC + tile * TILE + tid;   // row in batch
            skeys[tile * TILE + tid] = ((ull)__float_as_uint(s) << 32)
                                     | (unsigned int)(N - 1 - grow);
        }
        __syncthreads();                          // part[] reused next tile
    }

    // All-pairs rank among 256 distinct keys (broadcast LDS reads);
    // top 128 write themselves to their exact rank slot (sorted, no atomics).
    const ull mine = skeys[tid];
    int rank = 0;
    for (int j = 0; j < RPC; ++j)
        rank += (skeys[j] > mine) ? 1 : 0;
    if (rank < K)
        cand[(size_t)bid * K + rank] = mine;      // cached: re-read by stage 2
}

// --- Stage 2: exact top-K select over 4096 candidates (indices only) --------
// (BYTE-IDENTICAL to rounds 9-10.)
__global__ __launch_bounds__(1024) void topk_select_kernel(const ull* __restrict__ cand_in,
                                                           int* __restrict__ idx_out) {
    __shared__ ull keys[NCAND];                   // 32 KiB
    __shared__ unsigned int hist[256];
    __shared__ unsigned int seg[32];
    __shared__ ull s_prefix;
    __shared__ unsigned int s_krem;
    __shared__ int s_done;
    __shared__ unsigned int s_cnt;
    __shared__ ull sel[K];

    const int b    = blockIdx.x;
    const int tid  = threadIdx.x;
    const int lane = tid & 63;

    for (int i = tid; i < NCAND; i += 1024)
        keys[i] = cand_in[(size_t)b * NCAND + i];
    if (tid == 0) { s_prefix = 0ull; s_krem = K; s_done = 0; s_cnt = 0u; }
    __syncthreads();

    for (int p = 7; p >= 0; --p) {
        if (s_done) break;                         // uniform, barrier-separated
        const int shift = p * 8;
        const ull          prefix = s_prefix;
        const unsigned int krem   = s_krem;
        if (tid < 256) hist[tid] = 0u;
        __syncthreads();

        if (p == 7) {
            // Digits heavily duplicated: ballot-aggregated atomics.
            for (int i = tid; i < NCAND; i += 1024) {
                const unsigned int d = (unsigned int)(keys[i] >> 56);
                ull rem = __ballot(true);
                while (rem) {
                    const int leader = __ffsll(rem) - 1;
                    const unsigned int dl = __shfl(d, leader, 64);
                    const ull grp = __ballot(d == dl);
                    if (lane == leader) atomicAdd(&hist[dl], (unsigned int)__popcll(grp));
                    rem &= ~grp;
                }
            }
        } else {
            for (int i = tid; i < NCAND; i += 1024) {
                const ull key = keys[i];
                if ((key >> (shift + 8)) == (prefix >> (shift + 8)))
                    atomicAdd(&hist[(unsigned int)(key >> shift) & 255u], 1u);
            }
        }
        __syncthreads();

        if (tid < 32) {                            // segment sums of 8 bins
            unsigned int s = 0;
            #pragma unroll
            for (int d2 = 0; d2 < 8; ++d2) s += hist[tid * 8 + d2];
            seg[tid] = s;
        }
        __syncthreads();

        if (tid < 256) {
            unsigned int cnt_gt = 0;
            const int hiSeg = (tid >> 3) + 1;
            for (int s2 = hiSeg; s2 < 32; ++s2) cnt_gt += seg[s2];
            for (int d2 = tid + 1; d2 < hiSeg * 8; ++d2) cnt_gt += hist[d2];
            const unsigned int h = hist[tid];
            if (cnt_gt < krem && krem <= cnt_gt + h) {   // unique winner
                s_prefix = prefix | ((ull)tid << shift);
                s_krem   = krem - cnt_gt;
                if (h == krem - cnt_gt) s_done = 1;
            }
        }
        __syncthreads();
    }

    const ull T = s_prefix;
    for (int i = tid; i < NCAND; i += 1024) {
        const ull key = keys[i];
        if (key >= T) {
            const unsigned int pos = atomicAdd(&s_cnt, 1u);
            sel[pos] = key;
        }
    }
    __syncthreads();

    // Rank by all-pairs compare; write row index at its output rank.
    if (tid < K) {
        const ull key = sel[tid];
        int rank = 0;
        for (int j = 0; j < K; ++j) rank += (sel[j] > key) ? 1 : 0;
        idx_out[b * K + rank] = N - 1 - (int)(key & 0xFFFFFFFFu);
    }
}

// --- Stage 3: full-grid gather (NT on x-read and out-write) -----------------
// 2048 blocks x 256 threads; wave per output row, f4 per lane (1 KiB).
__global__ __launch_bounds__(256) void gather_kernel(const float* __restrict__ x,
                                                     const int* __restrict__ idx,
                                                     float* __restrict__ out) {
    const int row  = blockIdx.x * 4 + (threadIdx.x >> 6);    // 0 .. B*K-1
    const int lane = threadIdx.x & 63;
    const int b    = row >> 7;                                // / K
    const int src  = idx[row];
    const f4 v = __builtin_nontemporal_load(
        reinterpret_cast<const f4*>(x + ((size_t)b * N + src) * D) + lane);
    __builtin_nontemporal_store(
        v, reinterpret_cast<f4*>(out + (size_t)row * D) + lane);
}

extern "C" void kernel_launch(void* const* d_in, const int* in_sizes, int n_in,
                              void* d_out, int out_size, void* d_ws, size_t ws_size,
                              hipStream_t stream) {
    const float* x = (const float*)d_in[0];
    float* out = (float*)d_out;
    ull* cand = (ull*)d_ws;                        // B*NCAND u64 = 2 MiB
    int* idx  = (int*)(cand + (size_t)B * NCAND);  // B*K int = 32 KiB

    norm_select_kernel<<<B * CHUNKS, 256, 0, stream>>>(x, cand);
    topk_select_kernel<<<B, 1024, 0, stream>>>(cand, idx);
    gather_kernel<<<B * K / 4, 256, 0, stream>>>(x, idx, out);
}